// Round 7
// baseline (505.695 us; speedup 1.0000x reference)
//
#include <hip/hip_runtime.h>

#define NN     3072
#define INDIM  128
#define NH     4
#define DD     64
#define CC     256   // NH*DD
#define EE     8
#define NODE_T 8
#define NJC    (NN / 32)       // 96 j-chunks of 32
#define CHSZ   (NH * 16 * 32)  // 2048 shorts = one P fragment chunk (4 KB)
#define KSPLIT 4               // K-split in gat_pv (partial sums)
#define NCPS   (NJC / KSPLIT)  // 24 chunks per split

typedef short short8v __attribute__((ext_vector_type(8)));
typedef unsigned short ushort8v __attribute__((ext_vector_type(8)));
typedef float float4v __attribute__((ext_vector_type(4)));

__device__ __forceinline__ float bf2f(unsigned short u) {
    return __uint_as_float(((unsigned int)u) << 16);
}
__device__ __forceinline__ unsigned short f2bf(float f) {
    unsigned int u = __float_as_uint(f);
    u += 0x7fffu + ((u >> 16) & 1u);   // round-to-nearest-even
    return (unsigned short)(u >> 16);
}
__device__ __forceinline__ float rfl(float f) {   // force wave-uniform value to SGPR
    return __int_as_float(__builtin_amdgcn_readfirstlane(__float_as_int(f)));
}

// ---------------------------------------------------------------------------
// Kernel 1: h = x @ W. 8 nodes per block; thread owns channel c=tid.
// Writes htf in MFMA-B-FRAGMENT order (lane-contiguous dwordx4 reads in PV).
// ---------------------------------------------------------------------------
__global__ __launch_bounds__(256) void hproj(
    const float* __restrict__ x,      // (N,128)
    const float* __restrict__ W,      // (128,256)
    const float* __restrict__ a_src,  // (4,64)
    const float* __restrict__ a_dst,  // (4,64)
    unsigned short* __restrict__ htf, // ws: fragment-order bf16 (N*CC)
    float* __restrict__ s_src,        // ws: (N,4)
    float* __restrict__ s_dst)        // ws: (N,4)
{
    const int tid = threadIdx.x;
    const int n0  = blockIdx.x * NODE_T;
    const int h   = tid >> 6, lane = tid & 63;

    float acc[NODE_T] = {};
#pragma unroll 4
    for (int k = 0; k < INDIM; ++k) {
        const float wv = W[(size_t)k * CC + tid];
#pragma unroll
        for (int n = 0; n < NODE_T; ++n)
            acc[n] = fmaf(x[(size_t)(n0 + n) * INDIM + k], wv, acc[n]);
    }

    ushort8v hv;
#pragma unroll
    for (int n = 0; n < NODE_T; ++n) hv[n] = f2bf(acc[n]);
    unsigned short* dst = htf
        + (size_t)((h * 4 + (lane >> 4)) * NJC + (n0 >> 5)) * 512
        + (size_t)((((n0 >> 3) & 3) * 16 + (lane & 15)) * 8);
    *reinterpret_cast<ushort8v*>(dst) = hv;

    const float asv = a_src[h * DD + lane];
    const float adv = a_dst[h * DD + lane];
#pragma unroll
    for (int n = 0; n < NODE_T; ++n) {
        float s1 = acc[n] * asv, s2 = acc[n] * adv;
#pragma unroll
        for (int off = 32; off > 0; off >>= 1) {
            s1 += __shfl_xor(s1, off, 64);
            s2 += __shfl_xor(s2, off, 64);
        }
        if (lane == 0) {
            s_src[(size_t)(n0 + n) * NH + h] = s1;
            s_dst[(size_t)(n0 + n) * NH + h] = s2;
        }
    }
}

// ---------------------------------------------------------------------------
// Kernel 2: score — pure streaming, NO LDS, NO barriers, NO MFMA.
// Wave owns one i-row; lane owns 2 adjacent j per pass (24 passes of 128 j).
// All loads 8-64 B/lane contiguous; 7 loads continuously in flight per wave
// (no convoy/barrier duty-cycle loss — the round-5 fused loop's cap).
// p = adj ? exp(lrelu(score)) : 0 (logits bounded, no max — same as before).
// Writes P in MFMA-A-FRAGMENT order: Pf[i/16][j/32][h][i%16][j%32] bf16,
// dword (2 j) coalesced stores; and full row sums l[i][h] (no merge).
// ---------------------------------------------------------------------------
__global__ __launch_bounds__(256) void gat_score(
    const int* __restrict__ adj,      // (N,N)
    const float* __restrict__ ef,     // (N,N,8)
    const float* __restrict__ s_src,  // (N,4)
    const float* __restrict__ s_dst,  // (N,4)
    const float* __restrict__ ep_w,   // (8,4)
    const float* __restrict__ ep_b,   // (4,)
    unsigned short* __restrict__ Pf,  // ws: fragment-order P (N*N*NH bf16)
    float* __restrict__ lsum)         // ws: (N,4)
{
    const int tid  = threadIdx.x;
    const int w    = tid >> 6;
    const int lane = tid & 63;
    const int i    = blockIdx.x * 4 + w;

    // wave-uniform constants -> SGPR
    float epw[EE][NH];
#pragma unroll
    for (int e = 0; e < EE; ++e)
#pragma unroll
        for (int h = 0; h < NH; ++h) epw[e][h] = rfl(ep_w[e * NH + h]);
    float sb[NH];
#pragma unroll
    for (int h = 0; h < NH; ++h)
        sb[h] = rfl(s_src[(size_t)i * NH + h] + ep_b[h]);

    const size_t ro = (size_t)i * NN;
    // fragment-store base for this row: chunk row-block (i>>4), plane row (i&15)
    const size_t prow = (size_t)(i >> 4) * NJC * CHSZ + (size_t)(i & 15) * 32;

    float l_loc[NH] = {0.f, 0.f, 0.f, 0.f};

    for (int jb = 0; jb < NN; jb += 128) {
        const int j0 = jb + 2 * lane;
        const int2   a2  = *reinterpret_cast<const int2*>(adj + ro + j0);
        const float* ep  = ef + (ro + j0) * EE;
        const float4 e0  = *reinterpret_cast<const float4*>(ep);
        const float4 e1  = *reinterpret_cast<const float4*>(ep + 4);
        const float4 e2  = *reinterpret_cast<const float4*>(ep + 8);
        const float4 e3  = *reinterpret_cast<const float4*>(ep + 12);
        const float4 sda = *reinterpret_cast<const float4*>(s_dst + (size_t)j0 * NH);
        const float4 sdb = *reinterpret_cast<const float4*>(s_dst + (size_t)j0 * NH + 4);

        const float eva[EE]  = {e0.x, e0.y, e0.z, e0.w, e1.x, e1.y, e1.z, e1.w};
        const float evb[EE]  = {e2.x, e2.y, e2.z, e2.w, e3.x, e3.y, e3.z, e3.w};
        const float sdha[NH] = {sda.x, sda.y, sda.z, sda.w};
        const float sdhb[NH] = {sdb.x, sdb.y, sdb.z, sdb.w};

        // dword store target: chunk (j0>>5), in-plane offset (j0&31)
        unsigned int* pw = reinterpret_cast<unsigned int*>(
            Pf + prow + (size_t)(j0 >> 5) * CHSZ + (j0 & 31));

#pragma unroll
        for (int h = 0; h < NH; ++h) {
            float sa = sb[h] + sdha[h];
            float sc = sb[h] + sdhb[h];
#pragma unroll
            for (int e = 0; e < EE; ++e) {
                sa = fmaf(eva[e], epw[e][h], sa);
                sc = fmaf(evb[e], epw[e][h], sc);
            }
            sa = (sa > 0.f) ? sa : 0.2f * sa;
            sc = (sc > 0.f) ? sc : 0.2f * sc;
            const float pa = (a2.x == 0) ? 0.f : __expf(sa);
            const float pb = (a2.y == 0) ? 0.f : __expf(sc);
            const unsigned int ba = f2bf(pa), bb = f2bf(pb);
            l_loc[h] += bf2f((unsigned short)ba) + bf2f((unsigned short)bb);
            pw[h * 256] = ba | (bb << 16);   // h*512 shorts = h*256 dwords
        }
    }

    // full row sums (lanes held disjoint j)
#pragma unroll
    for (int h = 0; h < NH; ++h) {
        float v = l_loc[h];
#pragma unroll
        for (int off = 32; off > 0; off >>= 1) v += __shfl_xor(v, off, 64);
        if (lane == 0) lsum[(size_t)i * NH + h] = v;
    }
}

// ---------------------------------------------------------------------------
// Kernel 3: PV GEMM — NO LDS, NO barriers. Block = 16-row i-tile × 1/4 of K;
// wave = head. A from Pf (fragment-order, 1 KB contiguous per instr, L3-hot),
// B from htf (fragment-order, L2). 4 MFMA per 32-k chunk.
// ---------------------------------------------------------------------------
__global__ __launch_bounds__(256) void gat_pv(
    const unsigned short* __restrict__ Pf,
    const unsigned short* __restrict__ htf,
    float* __restrict__ out_part)      // ws: (KSPLIT,N,256)
{
    const int tid  = threadIdx.x;
    const int rw   = tid >> 6;        // head
    const int lane = tid & 63;
    const int l15  = lane & 15;
    const int q    = lane >> 4;
    const int bid  = blockIdx.x;
    const int s    = bid & (KSPLIT - 1);
    const int it   = bid >> 2;        // i-tile
    const int i0   = it * 16;

    float4v acc[4];
#pragma unroll
    for (int f = 0; f < 4; ++f) acc[f] = (float4v){0.f, 0.f, 0.f, 0.f};

    const unsigned short* Abase = Pf + (size_t)it * NJC * CHSZ
                                + (size_t)rw * 512 + (size_t)l15 * 32 + q * 8;
    const unsigned short* Bbase = htf + (size_t)lane * 8;

    for (int cc = 0; cc < NCPS; ++cc) {
        const int ch = s * NCPS + cc;
        const short8v a = *reinterpret_cast<const short8v*>(Abase + (size_t)ch * CHSZ);
#pragma unroll
        for (int f = 0; f < 4; ++f) {
            const short8v b = *reinterpret_cast<const short8v*>(
                Bbase + (size_t)((rw * 4 + f) * NJC + ch) * 512);
            acc[f] = __builtin_amdgcn_mfma_f32_16x16x32_bf16(a, b, acc[f], 0, 0, 0);
        }
    }

    // out partial: C row = q*4+reg, col = l15 (verified mapping)
#pragma unroll
    for (int f = 0; f < 4; ++f)
#pragma unroll
        for (int rg = 0; rg < 4; ++rg)
            out_part[((size_t)s * NN + i0 + q * 4 + rg) * CC + rw * DD + f * 16 + l15] = acc[f][rg];
}

// ---------------------------------------------------------------------------
// Kernel 4: merge KSPLIT partials, normalize by l, fused LayerNorm.
// ---------------------------------------------------------------------------
__global__ __launch_bounds__(256) void gat_ln(
    const float* __restrict__ out_part,  // (KSPLIT,N,256)
    const float* __restrict__ lsum,      // (N,4)
    const float* __restrict__ gamma,
    const float* __restrict__ beta,
    float* __restrict__ out)             // (N,256)
{
    const int tid = threadIdx.x, w = tid >> 6, lane = tid & 63;
    const int i = blockIdx.x * 4 + w;

    float v[4];
#pragma unroll
    for (int k = 0; k < 4; ++k) {
        float a = 0.f;
#pragma unroll
        for (int sp = 0; sp < KSPLIT; ++sp)
            a += out_part[((size_t)sp * NN + i) * CC + k * 64 + lane];
        v[k] = a / lsum[(size_t)i * NH + k];   // head of channel k*64+lane is k
    }

    float s1 = v[0] + v[1] + v[2] + v[3];
    float s2 = v[0] * v[0] + v[1] * v[1] + v[2] * v[2] + v[3] * v[3];
#pragma unroll
    for (int off = 32; off > 0; off >>= 1) {
        s1 += __shfl_xor(s1, off, 64);
        s2 += __shfl_xor(s2, off, 64);
    }
    const float mean = s1 * (1.f / CC);
    const float var  = s2 * (1.f / CC) - mean * mean;
    const float rstd = rsqrtf(var + 1e-5f);
    float* op = out + (size_t)i * CC;
#pragma unroll
    for (int k = 0; k < 4; ++k) {
        const int c = k * 64 + lane;
        op[c] = (v[k] - mean) * rstd * gamma[c] + beta[c];
    }
}

extern "C" void kernel_launch(void* const* d_in, const int* in_sizes, int n_in,
                              void* d_out, int out_size, void* d_ws, size_t ws_size,
                              hipStream_t stream) {
    const float* x     = (const float*)d_in[0];
    const int*   adj   = (const int*)d_in[1];
    const float* ef    = (const float*)d_in[2];
    const float* W     = (const float*)d_in[3];
    const float* a_src = (const float*)d_in[4];
    const float* a_dst = (const float*)d_in[5];
    const float* ep_w  = (const float*)d_in[6];
    const float* ep_b  = (const float*)d_in[7];
    const float* gamma = (const float*)d_in[8];
    const float* beta  = (const float*)d_in[9];

    // ws layout (~90.4 MB total; poison fill shows arena ~1.2 GB):
    //   s_src 48K | s_dst 48K | lsum 48K | htf 1.5M | Pf 75.5M | out_part 12.6M
    float* s_src = (float*)d_ws;
    float* s_dst = s_src + (size_t)NN * NH;
    float* lsum  = s_dst + (size_t)NN * NH;
    unsigned short* htf = (unsigned short*)(lsum + (size_t)NN * NH);
    unsigned short* Pf  = htf + (size_t)NN * CC;
    float* out_part = (float*)(Pf + (size_t)NN * NN * NH);
    (void)ws_size; (void)in_sizes; (void)n_in; (void)out_size;

    hipLaunchKernelGGL(hproj, dim3(NN / NODE_T), dim3(256), 0, stream,
                       x, W, a_src, a_dst, htf, s_src, s_dst);
    hipLaunchKernelGGL(gat_score, dim3(NN / 4), dim3(256), 0, stream,
                       adj, ef, s_src, s_dst, ep_w, ep_b, Pf, lsum);
    hipLaunchKernelGGL(gat_pv, dim3((NN / 16) * KSPLIT), dim3(256), 0, stream,
                       Pf, htf, out_part);
    hipLaunchKernelGGL(gat_ln, dim3(NN / 4), dim3(256), 0, stream,
                       out_part, lsum, gamma, beta, (float*)d_out);
}